// Round 4
// baseline (1210.462 us; speedup 1.0000x reference)
//
#include <hip/hip_runtime.h>

#define IN_C 512
#define OUT_C 512

// ---------------- degree count (int atomics) ----------------
__global__ void k_degree(const int* __restrict__ src, int E, int* __restrict__ deg) {
    int e = blockIdx.x * blockDim.x + threadIdx.x;
    if (e < E) atomicAdd(&deg[src[e]], 1);
}

// dinv[n] = 1/sqrt(deg[n]+1)   (+1 = self loop)
__global__ void k_dinv(const int* __restrict__ deg, int N, float* __restrict__ dinv) {
    int n = blockIdx.x * blockDim.x + threadIdx.x;
    if (n < N) dinv[n] = rsqrtf((float)(deg[n] + 1));
}

// ---------------- exclusive scan of deg -> row_start (single block) ----------------
__global__ void k_scan(const int* __restrict__ deg, int N, int* __restrict__ row_start) {
    __shared__ int s[1024];
    int t = threadIdx.x;
    int carry = 0;
    int nChunks = (N + 1023) / 1024;
    for (int c = 0; c < nChunks; ++c) {
        int i = c * 1024 + t;
        int v = (i < N) ? deg[i] : 0;
        s[t] = v;
        __syncthreads();
        // Hillis-Steele inclusive scan
        for (int off = 1; off < 1024; off <<= 1) {
            int tmp = (t >= off) ? s[t - off] : 0;
            __syncthreads();
            s[t] += tmp;
            __syncthreads();
        }
        if (i < N) row_start[i] = s[t] - v + carry;   // exclusive
        int total = s[1023];
        __syncthreads();   // protect s[] before next chunk overwrites
        carry += total;
    }
    if (t == 0) row_start[N] = carry;
}

// ---------------- CSR bucket fill ----------------
__global__ void k_fill(const int* __restrict__ src, const int* __restrict__ tar, int E,
                       const int* __restrict__ row_start, int* __restrict__ fill,
                       int* __restrict__ csr_tar) {
    int e = blockIdx.x * blockDim.x + threadIdx.x;
    if (e < E) {
        int s = src[e];
        int p = atomicAdd(&fill[s], 1);
        csr_tar[row_start[s] + p] = tar[e];
    }
}

// ---------------- fp32 GEMM: feat = x @ W^T + b ----------------
// 64x64 tile, BK=32, 256 threads, 4x4 microtile per thread.
#define BM 64
#define BN 64
#define BK 32

__global__ __launch_bounds__(256) void k_gemm(const float* __restrict__ x,
                                              const float* __restrict__ W,
                                              const float* __restrict__ bias,
                                              float* __restrict__ feat, int N) {
    __shared__ float As[BK][BM + 4];
    __shared__ float Bs[BK][BN + 4];
    int tid = threadIdx.x;
    int tx = tid & 15, ty = tid >> 4;
    int rowBase = blockIdx.y * BM;
    int colBase = blockIdx.x * BN;

    float4 acc[4];
    acc[0] = make_float4(0.f, 0.f, 0.f, 0.f);
    acc[1] = make_float4(0.f, 0.f, 0.f, 0.f);
    acc[2] = make_float4(0.f, 0.f, 0.f, 0.f);
    acc[3] = make_float4(0.f, 0.f, 0.f, 0.f);

    int lr  = tid >> 3;   // 0..31 row within tile-half
    int lc4 = tid & 7;    // float4 index within 32-wide K slab

    for (int k0 = 0; k0 < IN_C; k0 += BK) {
#pragma unroll
        for (int h = 0; h < 2; ++h) {
            int r = lr + h * 32;
            int grow = rowBase + r;
            float4 v = make_float4(0.f, 0.f, 0.f, 0.f);
            if (grow < N) v = *(const float4*)&x[(size_t)grow * IN_C + k0 + lc4 * 4];
            As[lc4 * 4 + 0][r] = v.x;
            As[lc4 * 4 + 1][r] = v.y;
            As[lc4 * 4 + 2][r] = v.z;
            As[lc4 * 4 + 3][r] = v.w;
            int gcol = colBase + r;   // always < 512
            float4 wv = *(const float4*)&W[(size_t)gcol * IN_C + k0 + lc4 * 4];
            Bs[lc4 * 4 + 0][r] = wv.x;
            Bs[lc4 * 4 + 1][r] = wv.y;
            Bs[lc4 * 4 + 2][r] = wv.z;
            Bs[lc4 * 4 + 3][r] = wv.w;
        }
        __syncthreads();
#pragma unroll
        for (int kk = 0; kk < BK; ++kk) {
            float4 a  = *(const float4*)&As[kk][ty * 4];
            float4 bb = *(const float4*)&Bs[kk][tx * 4];
            acc[0].x += a.x * bb.x; acc[0].y += a.x * bb.y; acc[0].z += a.x * bb.z; acc[0].w += a.x * bb.w;
            acc[1].x += a.y * bb.x; acc[1].y += a.y * bb.y; acc[1].z += a.y * bb.z; acc[1].w += a.y * bb.w;
            acc[2].x += a.z * bb.x; acc[2].y += a.z * bb.y; acc[2].z += a.z * bb.z; acc[2].w += a.z * bb.w;
            acc[3].x += a.w * bb.x; acc[3].y += a.w * bb.y; acc[3].z += a.w * bb.z; acc[3].w += a.w * bb.w;
        }
        __syncthreads();
    }

    float4 bv = *(const float4*)&bias[colBase + tx * 4];
#pragma unroll
    for (int i = 0; i < 4; ++i) {
        int grow = rowBase + ty * 4 + i;
        if (grow < N) {
            float4 o;
            o.x = acc[i].x + bv.x;
            o.y = acc[i].y + bv.y;
            o.z = acc[i].z + bv.z;
            o.w = acc[i].w + bv.w;
            *(float4*)&feat[(size_t)grow * OUT_C + colBase + tx * 4] = o;
        }
    }
}

// ---------------- aggregation: out[n] = sum_{tar in csr[n]} w*feat[tar] + feat[n]*dinv^2 ----------------
// one block (128 threads) per destination node; each thread owns one float4 (4 cols)
__global__ __launch_bounds__(128) void k_aggregate(const float4* __restrict__ feat4,
                                                   const float* __restrict__ dinv,
                                                   const int* __restrict__ row_start,
                                                   const int* __restrict__ csr_tar,
                                                   float4* __restrict__ out4, int N) {
    int n = blockIdx.x;
    int tid = threadIdx.x;   // 0..127 -> float4 index in row (512/4 = 128)
    __shared__ int   s_tar[128];
    __shared__ float s_w[128];
    float din = dinv[n];
    int rs = row_start[n], re = row_start[n + 1];
    float4 acc = make_float4(0.f, 0.f, 0.f, 0.f);

    for (int base = rs; base < re; base += 128) {
        int m = re - base;
        if (m > 128) m = 128;
        if (tid < m) {
            int t = csr_tar[base + tid];
            s_tar[tid] = t;
            s_w[tid] = din * dinv[t];
        }
        __syncthreads();
        for (int j = 0; j < m; ++j) {
            int t = s_tar[j];
            float w = s_w[j];
            float4 f = feat4[(size_t)t * 128 + tid];
            acc.x += w * f.x;
            acc.y += w * f.y;
            acc.z += w * f.z;
            acc.w += w * f.w;
        }
        __syncthreads();
    }

    float4 fs = feat4[(size_t)n * 128 + tid];
    float sw = din * din;   // 1/deg
    acc.x += sw * fs.x;
    acc.y += sw * fs.y;
    acc.z += sw * fs.z;
    acc.w += sw * fs.w;
    out4[(size_t)n * 128 + tid] = acc;
}

extern "C" void kernel_launch(void* const* d_in, const int* in_sizes, int n_in,
                              void* d_out, int out_size, void* d_ws, size_t ws_size,
                              hipStream_t stream) {
    const float* x    = (const float*)d_in[0];
    const int*   ei   = (const int*)d_in[1];
    const float* W    = (const float*)d_in[2];
    const float* bias = (const float*)d_in[3];
    float* out = (float*)d_out;

    int N = in_sizes[0] / IN_C;
    int E = in_sizes[1] / 2;
    const int* src = ei;
    const int* tar = ei + E;

    // workspace layout (needs ~110 MB)
    char* ws = (char*)d_ws;
    float* feat = (float*)ws;
    size_t off = (size_t)N * OUT_C * sizeof(float);
    float* dinv = (float*)(ws + off);      off += (size_t)N * sizeof(float);
    int* deg = (int*)(ws + off);           off += (size_t)N * sizeof(int);
    int* fill = (int*)(ws + off);          off += (size_t)N * sizeof(int);   // adjacent to deg
    int* row_start = (int*)(ws + off);     off += (size_t)(N + 1) * sizeof(int);
    int* csr_tar = (int*)(ws + off);       off += (size_t)E * sizeof(int);

    // zero deg + fill in one shot (they are adjacent)
    hipMemsetAsync(deg, 0, 2 * (size_t)N * sizeof(int), stream);

    k_degree<<<(E + 255) / 256, 256, 0, stream>>>(src, E, deg);
    k_dinv<<<(N + 255) / 256, 256, 0, stream>>>(deg, N, dinv);
    k_scan<<<1, 1024, 0, stream>>>(deg, N, row_start);
    k_fill<<<(E + 255) / 256, 256, 0, stream>>>(src, tar, E, row_start, fill, csr_tar);

    dim3 g(OUT_C / BN, (N + BM - 1) / BM);
    k_gemm<<<g, 256, 0, stream>>>(x, W, bias, feat, N);

    k_aggregate<<<N, 128, 0, stream>>>((const float4*)feat, dinv, row_start, csr_tar,
                                       (float4*)out, N);
}

// Round 6
// 716.192 us; speedup vs baseline: 1.6901x; 1.6901x over previous
//
#include <hip/hip_runtime.h>

#define IN_C 512
#define OUT_C 512

typedef __attribute__((ext_vector_type(4))) float f32x4;
typedef __attribute__((ext_vector_type(8))) short bf16x8;   // 8 bf16 in 4 VGPRs

__device__ __forceinline__ unsigned short f2bf_rne(float f) {
    unsigned int u = __float_as_uint(f);
    u += 0x7fffu + ((u >> 16) & 1u);   // round-to-nearest-even
    return (unsigned short)(u >> 16);
}
__device__ __forceinline__ float bflo(unsigned int u) { return __uint_as_float(u << 16); }
__device__ __forceinline__ float bfhi(unsigned int u) { return __uint_as_float(u & 0xffff0000u); }

// ---------------- fp32 -> bf16 convert (8 elems/thread) ----------------
__global__ void k_convert(const float* __restrict__ in, unsigned short* __restrict__ out, int n8) {
    int i = blockIdx.x * blockDim.x + threadIdx.x;
    if (i >= n8) return;
    const float4* in4 = (const float4*)in;
    float4 a = in4[i * 2], b = in4[i * 2 + 1];
    uint4 o;
    o.x = (unsigned)f2bf_rne(a.x) | ((unsigned)f2bf_rne(a.y) << 16);
    o.y = (unsigned)f2bf_rne(a.z) | ((unsigned)f2bf_rne(a.w) << 16);
    o.z = (unsigned)f2bf_rne(b.x) | ((unsigned)f2bf_rne(b.y) << 16);
    o.w = (unsigned)f2bf_rne(b.z) | ((unsigned)f2bf_rne(b.w) << 16);
    *(uint4*)&out[(size_t)i * 8] = o;
}

// ---------------- degree count ----------------
__global__ void k_degree(const int* __restrict__ src, int E, int* __restrict__ deg) {
    int e = blockIdx.x * blockDim.x + threadIdx.x;
    if (e < E) atomicAdd(&deg[src[e]], 1);
}

__global__ void k_dinv(const int* __restrict__ deg, int N, float* __restrict__ dinv) {
    int n = blockIdx.x * blockDim.x + threadIdx.x;
    if (n < N) dinv[n] = rsqrtf((float)(deg[n] + 1));
}

// ---------------- exclusive scan (single block, wave-shuffle based) ----------------
__global__ void k_scan(const int* __restrict__ deg, int N, int* __restrict__ row_start) {
    __shared__ int wsum[16];
    int t = threadIdx.x;
    int wave = t >> 6, lane = t & 63;
    int carry = 0;
    int nChunks = (N + 1023) >> 10;
    for (int c = 0; c < nChunks; ++c) {
        int i = (c << 10) + t;
        int v = (i < N) ? deg[i] : 0;
        int s = v;
#pragma unroll
        for (int off = 1; off < 64; off <<= 1) {
            int u = __shfl_up(s, off, 64);
            if (lane >= off) s += u;
        }
        if (lane == 63) wsum[wave] = s;
        __syncthreads();
        if (wave == 0 && lane < 16) {
            int ws = wsum[lane];
#pragma unroll
            for (int off = 1; off < 16; off <<= 1) {
                int u = __shfl_up(ws, off, 64);
                if (lane >= off) ws += u;
            }
            wsum[lane] = ws;   // inclusive wave totals
        }
        __syncthreads();
        int waveOff = (wave == 0) ? 0 : wsum[wave - 1];
        if (i < N) row_start[i] = s - v + waveOff + carry;   // exclusive
        int total = wsum[15];
        __syncthreads();   // protect wsum before next chunk
        carry += total;
    }
    if (t == 0) row_start[N] = carry;
}

// ---------------- CSR bucket fill ----------------
__global__ void k_fill(const int* __restrict__ src, const int* __restrict__ tar, int E,
                       const int* __restrict__ row_start, int* __restrict__ fill,
                       int* __restrict__ csr_tar) {
    int e = blockIdx.x * blockDim.x + threadIdx.x;
    if (e < E) {
        int s = src[e];
        int p = atomicAdd(&fill[s], 1);
        csr_tar[row_start[s] + p] = tar[e];
    }
}

// ---------------- bf16 MFMA GEMM: featb = bf16(x @ W^T + b) ----------------
// 128x128 tile, 4 waves in 2x2, each wave 64x64 = 4x4 fragments of 16x16x32.
// A frag: lane l holds x[row = base + (l&15)][k = k0 + (l>>4)*8 + i], i=0..7
// B frag: lane l holds W[col = base + (l&15)][k = k0 + (l>>4)*8 + i]
// C/D:    col = lane&15, row = (lane>>4)*4 + reg   [verified mapping]
__global__ __launch_bounds__(256) void k_gemm_mfma(const unsigned short* __restrict__ xb,
                                                   const unsigned short* __restrict__ wb,
                                                   const float* __restrict__ bias,
                                                   unsigned short* __restrict__ featb, int N) {
    int tid = threadIdx.x;
    int wave = tid >> 6, lane = tid & 63;
    int wr = wave >> 1, wc = wave & 1;
    int rowBase = blockIdx.y * 128 + wr * 64;
    int colBase = blockIdx.x * 128 + wc * 64;
    int r0 = lane & 15;
    int kg = lane >> 4;           // 0..3

    f32x4 acc[4][4];
#pragma unroll
    for (int mi = 0; mi < 4; ++mi)
#pragma unroll
        for (int ni = 0; ni < 4; ++ni)
            acc[mi][ni] = (f32x4){0.f, 0.f, 0.f, 0.f};

    for (int k0 = 0; k0 < IN_C; k0 += 32) {
        bf16x8 a[4], b[4];
#pragma unroll
        for (int mi = 0; mi < 4; ++mi) {
            int r = rowBase + mi * 16 + r0;
            if (r > N - 1) r = N - 1;                 // clamp; stores guarded below
            a[mi] = *(const bf16x8*)&xb[(size_t)r * IN_C + k0 + kg * 8];
        }
#pragma unroll
        for (int ni = 0; ni < 4; ++ni) {
            int ccol = colBase + ni * 16 + r0;        // always < 512
            b[ni] = *(const bf16x8*)&wb[(size_t)ccol * IN_C + k0 + kg * 8];
        }
#pragma unroll
        for (int mi = 0; mi < 4; ++mi)
#pragma unroll
            for (int ni = 0; ni < 4; ++ni)
                acc[mi][ni] = __builtin_amdgcn_mfma_f32_16x16x32_bf16(a[mi], b[ni], acc[mi][ni], 0, 0, 0);
    }

    float bv[4];
#pragma unroll
    for (int ni = 0; ni < 4; ++ni) bv[ni] = bias[colBase + ni * 16 + r0];

#pragma unroll
    for (int mi = 0; mi < 4; ++mi) {
#pragma unroll
        for (int reg = 0; reg < 4; ++reg) {
            int grow = rowBase + mi * 16 + kg * 4 + reg;
            if (grow < N) {
#pragma unroll
                for (int ni = 0; ni < 4; ++ni) {
                    float v = acc[mi][ni][reg] + bv[ni];
                    featb[(size_t)grow * OUT_C + colBase + ni * 16 + r0] = f2bf_rne(v);
                }
            }
        }
    }
}

// ---------------- aggregation: one wave per node, bf16 gather, fp32 accumulate ----------------
__global__ __launch_bounds__(256) void k_aggregate(const unsigned short* __restrict__ featb,
                                                   const float* __restrict__ dinv,
                                                   const int* __restrict__ row_start,
                                                   const int* __restrict__ csr_tar,
                                                   float* __restrict__ out, int N) {
    int wave = threadIdx.x >> 6, lane = threadIdx.x & 63;
    int n = blockIdx.x * 4 + wave;
    if (n >= N) return;
    float din = dinv[n];
    int rs = row_start[n], re = row_start[n + 1];
    float accf[8] = {0.f, 0.f, 0.f, 0.f, 0.f, 0.f, 0.f, 0.f};

    for (int base = rs; base < re; base += 64) {
        int m = re - base;
        if (m > 64) m = 64;
        int t_l = 0;
        float w_l = 0.f;
        if (lane < m) {
            t_l = csr_tar[base + lane];
            w_l = din * dinv[t_l];
        }
        for (int j = 0; j < m; ++j) {
            int t = __shfl(t_l, j, 64);
            float w = __shfl(w_l, j, 64);
            uint4 v = *(const uint4*)&featb[(size_t)t * OUT_C + lane * 8];
            accf[0] += w * bflo(v.x);
            accf[1] += w * bfhi(v.x);
            accf[2] += w * bflo(v.y);
            accf[3] += w * bfhi(v.y);
            accf[4] += w * bflo(v.z);
            accf[5] += w * bfhi(v.z);
            accf[6] += w * bflo(v.w);
            accf[7] += w * bfhi(v.w);
        }
    }

    // self contribution: feat[n] * dinv^2
    {
        uint4 v = *(const uint4*)&featb[(size_t)n * OUT_C + lane * 8];
        float sw = din * din;
        accf[0] += sw * bflo(v.x);
        accf[1] += sw * bfhi(v.x);
        accf[2] += sw * bflo(v.y);
        accf[3] += sw * bfhi(v.y);
        accf[4] += sw * bflo(v.z);
        accf[5] += sw * bfhi(v.z);
        accf[6] += sw * bflo(v.w);
        accf[7] += sw * bfhi(v.w);
    }
    float4 o0 = {accf[0], accf[1], accf[2], accf[3]};
    float4 o1 = {accf[4], accf[5], accf[6], accf[7]};
    *(float4*)&out[(size_t)n * OUT_C + lane * 8] = o0;
    *(float4*)&out[(size_t)n * OUT_C + lane * 8 + 4] = o1;
}

extern "C" void kernel_launch(void* const* d_in, const int* in_sizes, int n_in,
                              void* d_out, int out_size, void* d_ws, size_t ws_size,
                              hipStream_t stream) {
    const float* x    = (const float*)d_in[0];
    const int*   ei   = (const int*)d_in[1];
    const float* W    = (const float*)d_in[2];
    const float* bias = (const float*)d_in[3];
    float* out = (float*)d_out;

    int N = in_sizes[0] / IN_C;     // 50000
    int E = in_sizes[1] / 2;        // 1600000
    const int* src = ei;
    const int* tar = ei + E;

    // workspace layout (~103.7 MB); csr_tar aliases xb (dead after GEMM)
    char* ws = (char*)d_ws;
    unsigned short* featb = (unsigned short*)ws;                      // 51.2 MB
    size_t off = (size_t)N * OUT_C * sizeof(unsigned short);
    unsigned short* xb = (unsigned short*)(ws + off);                 // 51.2 MB
    size_t xb_off = off;
    off += (size_t)N * IN_C * sizeof(unsigned short);
    unsigned short* wb = (unsigned short*)(ws + off);                 // 0.52 MB
    off += (size_t)OUT_C * IN_C * sizeof(unsigned short);
    float* dinv = (float*)(ws + off);      off += (size_t)N * sizeof(float);
    int* deg = (int*)(ws + off);           off += (size_t)N * sizeof(int);
    int* fill = (int*)(ws + off);          off += (size_t)N * sizeof(int);   // adjacent to deg
    int* row_start = (int*)(ws + off);     off += (size_t)(N + 1) * sizeof(int);
    int* csr_tar = (int*)(ws + xb_off);    // reuse xb region after GEMM

    // ---- phase 1: convert + GEMM (xb live) ----
    int n8x = N * IN_C / 8;
    k_convert<<<(n8x + 255) / 256, 256, 0, stream>>>(x, xb, n8x);
    int n8w = OUT_C * IN_C / 8;
    k_convert<<<(n8w + 255) / 256, 256, 0, stream>>>(W, wb, n8w);
    dim3 g(OUT_C / 128, (N + 127) / 128);
    k_gemm_mfma<<<g, 256, 0, stream>>>(xb, wb, bias, featb, N);

    // ---- phase 2: CSR build (csr_tar overwrites xb; GEMM already consumed it) ----
    hipMemsetAsync(deg, 0, 2 * (size_t)N * sizeof(int), stream);
    k_degree<<<(E + 255) / 256, 256, 0, stream>>>(src, E, deg);
    k_dinv<<<(N + 255) / 256, 256, 0, stream>>>(deg, N, dinv);
    k_scan<<<1, 1024, 0, stream>>>(deg, N, row_start);
    k_fill<<<(E + 255) / 256, 256, 0, stream>>>(src, tar, E, row_start, fill, csr_tar);

    // ---- phase 3: aggregate ----
    k_aggregate<<<(N + 3) / 4, 256, 0, stream>>>(featb, dinv, row_start, csr_tar, out, N);
}

// Round 11
// 681.093 us; speedup vs baseline: 1.7772x; 1.0515x over previous
//
#include <hip/hip_runtime.h>

#define IN_C 512
#define OUT_C 512

typedef __attribute__((ext_vector_type(4))) float f32x4;
typedef __attribute__((ext_vector_type(8))) short bf16x8;   // 8 bf16 in 4 VGPRs

__device__ __forceinline__ unsigned short f2bf_rne(float f) {
    unsigned int u = __float_as_uint(f);
    u += 0x7fffu + ((u >> 16) & 1u);   // round-to-nearest-even
    return (unsigned short)(u >> 16);
}
__device__ __forceinline__ float bflo(unsigned int u) { return __uint_as_float(u << 16); }
__device__ __forceinline__ float bfhi(unsigned int u) { return __uint_as_float(u & 0xffff0000u); }

// ---------------- fp32 -> bf16 convert (8 elems/thread) ----------------
__global__ void k_convert(const float* __restrict__ in, unsigned short* __restrict__ out, int n8) {
    int i = blockIdx.x * blockDim.x + threadIdx.x;
    if (i >= n8) return;
    const float4* in4 = (const float4*)in;
    float4 a = in4[i * 2], b = in4[i * 2 + 1];
    uint4 o;
    o.x = (unsigned)f2bf_rne(a.x) | ((unsigned)f2bf_rne(a.y) << 16);
    o.y = (unsigned)f2bf_rne(a.z) | ((unsigned)f2bf_rne(a.w) << 16);
    o.z = (unsigned)f2bf_rne(b.x) | ((unsigned)f2bf_rne(b.y) << 16);
    o.w = (unsigned)f2bf_rne(b.z) | ((unsigned)f2bf_rne(b.w) << 16);
    *(uint4*)&out[(size_t)i * 8] = o;
}

// ---------------- degree count ----------------
__global__ void k_degree(const int* __restrict__ src, int E, int* __restrict__ deg) {
    int e = blockIdx.x * blockDim.x + threadIdx.x;
    if (e < E) atomicAdd(&deg[src[e]], 1);
}

// ---------------- scan phase 1: per-block (1024) local exclusive scan + dinv ----------------
__global__ __launch_bounds__(1024) void k_scan1(const int* __restrict__ deg, int N,
                                                int* __restrict__ row_start,
                                                int* __restrict__ bsum,
                                                float* __restrict__ dinv) {
    __shared__ int wsum[16];
    int t = threadIdx.x;
    int wave = t >> 6, lane = t & 63;
    int i = blockIdx.x * 1024 + t;
    int v = (i < N) ? deg[i] : 0;
    if (i < N) dinv[i] = rsqrtf((float)(v + 1));
    int s = v;
#pragma unroll
    for (int off = 1; off < 64; off <<= 1) {
        int u = __shfl_up(s, off, 64);
        if (lane >= off) s += u;
    }
    if (lane == 63) wsum[wave] = s;
    __syncthreads();
    if (wave == 0 && lane < 16) {
        int ws = wsum[lane];
#pragma unroll
        for (int off = 1; off < 16; off <<= 1) {
            int u = __shfl_up(ws, off, 64);
            if (lane >= off) ws += u;
        }
        wsum[lane] = ws;   // inclusive wave totals
    }
    __syncthreads();
    int waveOff = (wave == 0) ? 0 : wsum[wave - 1];
    if (i < N) row_start[i] = s - v + waveOff;      // block-local exclusive
    if (t == 0) bsum[blockIdx.x] = wsum[15];        // block total
}

// ---------------- scan phase 2: one wave scans the <=64 block sums ----------------
__global__ void k_scan2(int* __restrict__ bsum, int nb) {
    int lane = threadIdx.x & 63;
    int v = (lane < nb) ? bsum[lane] : 0;
    int s = v;
#pragma unroll
    for (int off = 1; off < 64; off <<= 1) {
        int u = __shfl_up(s, off, 64);
        if (lane >= off) s += u;
    }
    if (lane < nb) bsum[lane] = s - v;   // exclusive block offsets
    if (lane == 63) bsum[nb] = s;        // grand total (= E)
}

// ---------------- scan phase 3: add block offsets; write row_start[N] ----------------
__global__ void k_scan3(int* __restrict__ row_start, const int* __restrict__ bsum, int N, int nb) {
    int i = blockIdx.x * blockDim.x + threadIdx.x;
    if (i < N) row_start[i] += bsum[i >> 10];
    if (i == 0) row_start[N] = bsum[nb];
}

// ---------------- CSR bucket fill ----------------
__global__ void k_fill(const int* __restrict__ src, const int* __restrict__ tar, int E,
                       const int* __restrict__ row_start, int* __restrict__ fill,
                       int* __restrict__ csr_tar) {
    int e = blockIdx.x * blockDim.x + threadIdx.x;
    if (e < E) {
        int s = src[e];
        int p = atomicAdd(&fill[s], 1);
        csr_tar[row_start[s] + p] = tar[e];
    }
}

// ---------------- bf16 MFMA GEMM: featb = bf16(x @ W^T + b) ----------------
// (unchanged — kept identical for attribution; rewrite pending its measured
//  duration once it surfaces in top-5)
__global__ __launch_bounds__(256) void k_gemm_mfma(const unsigned short* __restrict__ xb,
                                                   const unsigned short* __restrict__ wb,
                                                   const float* __restrict__ bias,
                                                   unsigned short* __restrict__ featb, int N) {
    int tid = threadIdx.x;
    int wave = tid >> 6, lane = tid & 63;
    int wr = wave >> 1, wc = wave & 1;
    int rowBase = blockIdx.y * 128 + wr * 64;
    int colBase = blockIdx.x * 128 + wc * 64;
    int r0 = lane & 15;
    int kg = lane >> 4;           // 0..3

    f32x4 acc[4][4];
#pragma unroll
    for (int mi = 0; mi < 4; ++mi)
#pragma unroll
        for (int ni = 0; ni < 4; ++ni)
            acc[mi][ni] = (f32x4){0.f, 0.f, 0.f, 0.f};

    for (int k0 = 0; k0 < IN_C; k0 += 32) {
        bf16x8 a[4], b[4];
#pragma unroll
        for (int mi = 0; mi < 4; ++mi) {
            int r = rowBase + mi * 16 + r0;
            if (r > N - 1) r = N - 1;                 // clamp; stores guarded below
            a[mi] = *(const bf16x8*)&xb[(size_t)r * IN_C + k0 + kg * 8];
        }
#pragma unroll
        for (int ni = 0; ni < 4; ++ni) {
            int ccol = colBase + ni * 16 + r0;        // always < 512
            b[ni] = *(const bf16x8*)&wb[(size_t)ccol * IN_C + k0 + kg * 8];
        }
#pragma unroll
        for (int mi = 0; mi < 4; ++mi)
#pragma unroll
            for (int ni = 0; ni < 4; ++ni)
                acc[mi][ni] = __builtin_amdgcn_mfma_f32_16x16x32_bf16(a[mi], b[ni], acc[mi][ni], 0, 0, 0);
    }

    float bv[4];
#pragma unroll
    for (int ni = 0; ni < 4; ++ni) bv[ni] = bias[colBase + ni * 16 + r0];

#pragma unroll
    for (int mi = 0; mi < 4; ++mi) {
#pragma unroll
        for (int reg = 0; reg < 4; ++reg) {
            int grow = rowBase + mi * 16 + kg * 4 + reg;
            if (grow < N) {
#pragma unroll
                for (int ni = 0; ni < 4; ++ni) {
                    float v = acc[mi][ni][reg] + bv[ni];
                    featb[(size_t)grow * OUT_C + colBase + ni * 16 + r0] = f2bf_rne(v);
                }
            }
        }
    }
}

// ---------------- aggregation: one wave per node, 4-deep gather pipeline ----------------
__device__ __forceinline__ void acc8(float* accf, uint4 v, float wgt) {
    accf[0] += wgt * bflo(v.x); accf[1] += wgt * bfhi(v.x);
    accf[2] += wgt * bflo(v.y); accf[3] += wgt * bfhi(v.y);
    accf[4] += wgt * bflo(v.z); accf[5] += wgt * bfhi(v.z);
    accf[6] += wgt * bflo(v.w); accf[7] += wgt * bfhi(v.w);
}

__global__ __launch_bounds__(256) void k_aggregate(const unsigned short* __restrict__ featb,
                                                   const float* __restrict__ dinv,
                                                   const int* __restrict__ row_start,
                                                   const int* __restrict__ csr_tar,
                                                   float* __restrict__ out, int N) {
    int wave = threadIdx.x >> 6, lane = threadIdx.x & 63;
    int n = blockIdx.x * 4 + wave;
    if (n >= N) return;
    float din = dinv[n];
    int rs = row_start[n], re = row_start[n + 1];
    float accf[8] = {0.f, 0.f, 0.f, 0.f, 0.f, 0.f, 0.f, 0.f};

    for (int base = rs; base < re; base += 64) {
        int m = re - base;
        if (m > 64) m = 64;
        int t_l = 0;
        float w_l = 0.f;
        if (lane < m) {
            t_l = csr_tar[base + lane];
            w_l = din * dinv[t_l];
        }
        int j = 0;
        for (; j + 4 <= m; j += 4) {
            int t0 = __shfl(t_l, j, 64),     t1 = __shfl(t_l, j + 1, 64);
            int t2 = __shfl(t_l, j + 2, 64), t3 = __shfl(t_l, j + 3, 64);
            float w0 = __shfl(w_l, j, 64),     w1 = __shfl(w_l, j + 1, 64);
            float w2 = __shfl(w_l, j + 2, 64), w3 = __shfl(w_l, j + 3, 64);
            uint4 v0 = *(const uint4*)&featb[(size_t)t0 * OUT_C + lane * 8];
            uint4 v1 = *(const uint4*)&featb[(size_t)t1 * OUT_C + lane * 8];
            uint4 v2 = *(const uint4*)&featb[(size_t)t2 * OUT_C + lane * 8];
            uint4 v3 = *(const uint4*)&featb[(size_t)t3 * OUT_C + lane * 8];
            acc8(accf, v0, w0);
            acc8(accf, v1, w1);
            acc8(accf, v2, w2);
            acc8(accf, v3, w3);
        }
        for (; j < m; ++j) {
            int t = __shfl(t_l, j, 64);
            float w = __shfl(w_l, j, 64);
            uint4 v = *(const uint4*)&featb[(size_t)t * OUT_C + lane * 8];
            acc8(accf, v, w);
        }
    }

    // self contribution: feat[n] * dinv^2
    {
        uint4 v = *(const uint4*)&featb[(size_t)n * OUT_C + lane * 8];
        acc8(accf, v, din * din);
    }
    float4 o0 = {accf[0], accf[1], accf[2], accf[3]};
    float4 o1 = {accf[4], accf[5], accf[6], accf[7]};
    *(float4*)&out[(size_t)n * OUT_C + lane * 8] = o0;
    *(float4*)&out[(size_t)n * OUT_C + lane * 8 + 4] = o1;
}

extern "C" void kernel_launch(void* const* d_in, const int* in_sizes, int n_in,
                              void* d_out, int out_size, void* d_ws, size_t ws_size,
                              hipStream_t stream) {
    const float* x    = (const float*)d_in[0];
    const int*   ei   = (const int*)d_in[1];
    const float* W    = (const float*)d_in[2];
    const float* bias = (const float*)d_in[3];
    float* out = (float*)d_out;

    int N = in_sizes[0] / IN_C;     // 50000
    int E = in_sizes[1] / 2;        // 1600000
    const int* src = ei;
    const int* tar = ei + E;
    int nb = (N + 1023) >> 10;      // scan blocks (49)

    // workspace layout (~103.7 MB); csr_tar aliases xb (dead after GEMM)
    char* ws = (char*)d_ws;
    unsigned short* featb = (unsigned short*)ws;                      // 51.2 MB
    size_t off = (size_t)N * OUT_C * sizeof(unsigned short);
    unsigned short* xb = (unsigned short*)(ws + off);                 // 51.2 MB
    size_t xb_off = off;
    off += (size_t)N * IN_C * sizeof(unsigned short);
    unsigned short* wb = (unsigned short*)(ws + off);                 // 0.52 MB
    off += (size_t)OUT_C * IN_C * sizeof(unsigned short);
    float* dinv = (float*)(ws + off);      off += (size_t)N * sizeof(float);
    int* deg = (int*)(ws + off);           off += (size_t)N * sizeof(int);
    int* fill = (int*)(ws + off);          off += (size_t)N * sizeof(int);   // adjacent to deg
    int* row_start = (int*)(ws + off);     off += (size_t)(N + 1) * sizeof(int);
    int* bsum = (int*)(ws + off);          off += (size_t)(nb + 1) * sizeof(int);
    int* csr_tar = (int*)(ws + xb_off);    // reuse xb region after GEMM

    // ---- phase 1: convert + GEMM (xb live) ----
    int n8x = N * IN_C / 8;
    k_convert<<<(n8x + 255) / 256, 256, 0, stream>>>(x, xb, n8x);
    int n8w = OUT_C * IN_C / 8;
    k_convert<<<(n8w + 255) / 256, 256, 0, stream>>>(W, wb, n8w);
    dim3 g(OUT_C / 128, (N + 127) / 128);
    k_gemm_mfma<<<g, 256, 0, stream>>>(xb, wb, bias, featb, N);

    // ---- phase 2: CSR build (csr_tar overwrites xb; GEMM already consumed it) ----
    (void)hipMemsetAsync(deg, 0, 2 * (size_t)N * sizeof(int), stream);
    k_degree<<<(E + 255) / 256, 256, 0, stream>>>(src, E, deg);
    k_scan1<<<nb, 1024, 0, stream>>>(deg, N, row_start, bsum, dinv);
    k_scan2<<<1, 64, 0, stream>>>(bsum, nb);
    k_scan3<<<(N + 255) / 256, 256, 0, stream>>>(row_start, bsum, N, nb);
    k_fill<<<(E + 255) / 256, 256, 0, stream>>>(src, tar, E, row_start, fill, csr_tar);

    // ---- phase 3: aggregate ----
    k_aggregate<<<(N + 3) / 4, 256, 0, stream>>>(featb, dinv, row_start, csr_tar, out, N);
}

// Round 13
// 635.308 us; speedup vs baseline: 1.9053x; 1.0721x over previous
//
#include <hip/hip_runtime.h>

#define IN_C 512
#define OUT_C 512

typedef __attribute__((ext_vector_type(4))) float f32x4;
typedef __attribute__((ext_vector_type(8))) short bf16x8;   // 8 bf16 in 4 VGPRs

__device__ __forceinline__ unsigned short f2bf_rne(float f) {
    unsigned int u = __float_as_uint(f);
    u += 0x7fffu + ((u >> 16) & 1u);   // round-to-nearest-even
    return (unsigned short)(u >> 16);
}
__device__ __forceinline__ float bflo(unsigned int u) { return __uint_as_float(u << 16); }
__device__ __forceinline__ float bfhi(unsigned int u) { return __uint_as_float(u & 0xffff0000u); }

// ---------------- fp32 -> bf16 convert (W only; x is fused into GEMM) ----------------
__global__ void k_convert(const float* __restrict__ in, unsigned short* __restrict__ out, int n8) {
    int i = blockIdx.x * blockDim.x + threadIdx.x;
    if (i >= n8) return;
    const float4* in4 = (const float4*)in;
    float4 a = in4[i * 2], b = in4[i * 2 + 1];
    uint4 o;
    o.x = (unsigned)f2bf_rne(a.x) | ((unsigned)f2bf_rne(a.y) << 16);
    o.y = (unsigned)f2bf_rne(a.z) | ((unsigned)f2bf_rne(a.w) << 16);
    o.z = (unsigned)f2bf_rne(b.x) | ((unsigned)f2bf_rne(b.y) << 16);
    o.w = (unsigned)f2bf_rne(b.z) | ((unsigned)f2bf_rne(b.w) << 16);
    *(uint4*)&out[(size_t)i * 8] = o;
}

// ---------------- degree count ----------------
__global__ void k_degree(const int* __restrict__ src, int E, int* __restrict__ deg) {
    int e = blockIdx.x * blockDim.x + threadIdx.x;
    if (e < E) atomicAdd(&deg[src[e]], 1);
}

// ---------------- scan phase 1: per-block (1024) local exclusive scan + dinv ----------------
__global__ __launch_bounds__(1024) void k_scan1(const int* __restrict__ deg, int N,
                                                int* __restrict__ row_start,
                                                int* __restrict__ bsum,
                                                float* __restrict__ dinv) {
    __shared__ int wsum[16];
    int t = threadIdx.x;
    int wave = t >> 6, lane = t & 63;
    int i = blockIdx.x * 1024 + t;
    int v = (i < N) ? deg[i] : 0;
    if (i < N) dinv[i] = rsqrtf((float)(v + 1));
    int s = v;
#pragma unroll
    for (int off = 1; off < 64; off <<= 1) {
        int u = __shfl_up(s, off, 64);
        if (lane >= off) s += u;
    }
    if (lane == 63) wsum[wave] = s;
    __syncthreads();
    if (wave == 0 && lane < 16) {
        int ws = wsum[lane];
#pragma unroll
        for (int off = 1; off < 16; off <<= 1) {
            int u = __shfl_up(ws, off, 64);
            if (lane >= off) ws += u;
        }
        wsum[lane] = ws;   // inclusive wave totals
    }
    __syncthreads();
    int waveOff = (wave == 0) ? 0 : wsum[wave - 1];
    if (i < N) row_start[i] = s - v + waveOff;      // block-local exclusive
    if (t == 0) bsum[blockIdx.x] = wsum[15];        // block total
}

// ---------------- scan phase 2 (fused): add block-prefix; row_start[N] = E ----------------
// each 256-thread block computes prefix-sum of bsum[0..chunk-1] itself (<=64 entries)
__global__ void k_scan3(int* __restrict__ row_start, const int* __restrict__ bsum,
                        int N, int E) {
    int lane = threadIdx.x & 63;
    int chunk = blockIdx.x >> 2;            // which 1024-chunk this block belongs to
    int v = (lane < chunk) ? bsum[lane] : 0;
#pragma unroll
    for (int off = 1; off < 64; off <<= 1)
        v += __shfl_xor(v, off, 64);        // all lanes end with total
    int i = blockIdx.x * 256 + threadIdx.x;
    if (i < N) row_start[i] += v;
    if (i == 0) row_start[N] = E;
}

// ---------------- CSR bucket fill ----------------
__global__ void k_fill(const int* __restrict__ src, const int* __restrict__ tar, int E,
                       const int* __restrict__ row_start, int* __restrict__ fill,
                       int* __restrict__ csr_tar) {
    int e = blockIdx.x * blockDim.x + threadIdx.x;
    if (e < E) {
        int s = src[e];
        int p = atomicAdd(&fill[s], 1);
        csr_tar[row_start[s] + p] = tar[e];
    }
}

// ---------------- fused convert+GEMM: featb = bf16(x @ W^T + b) ----------------
// 128x128 tile, BK=32, LDS-staged. A staged from fp32 x with in-register bf16
// convert (coalesced float4 loads); B staged from pre-converted wb (L2-hot).
// LDS row stride 40 bf16 (80B = 20 banks): ds_read_b128 worst case 2-way (free).
__global__ __launch_bounds__(256) void k_gemm_fused(const float* __restrict__ x,
                                                    const unsigned short* __restrict__ wb,
                                                    const float* __restrict__ bias,
                                                    unsigned short* __restrict__ featb, int N) {
    __shared__ unsigned short As[128 * 40];
    __shared__ unsigned short Bs[128 * 40];
    int tid = threadIdx.x;
    int wave = tid >> 6, lane = tid & 63;
    int wr = wave >> 1, wc = wave & 1;
    int rowBase = blockIdx.y * 128;
    int colBase = blockIdx.x * 128;
    int r0 = lane & 15, kg = lane >> 4;

    f32x4 acc[4][4];
#pragma unroll
    for (int mi = 0; mi < 4; ++mi)
#pragma unroll
        for (int ni = 0; ni < 4; ++ni)
            acc[mi][ni] = (f32x4){0.f, 0.f, 0.f, 0.f};

    for (int k0 = 0; k0 < IN_C; k0 += 32) {
        // stage A: 128 rows x 32 k fp32 -> bf16; thread t chunk i covers (row, q)
#pragma unroll
        for (int i = 0; i < 4; ++i) {
            int idx = tid + i * 256;          // 0..1023
            int row = idx >> 3, q = idx & 7;  // q: float4 index in 32-float slab
            int grow = rowBase + row;
            if (grow > N - 1) grow = N - 1;   // clamp (stores guarded)
            float4 v = *(const float4*)&x[(size_t)grow * IN_C + k0 + q * 4];
            ushort4 b4;
            b4.x = f2bf_rne(v.x); b4.y = f2bf_rne(v.y);
            b4.z = f2bf_rne(v.z); b4.w = f2bf_rne(v.w);
            *(ushort4*)&As[row * 40 + q * 4] = b4;
        }
        // stage B: 128 cols x 32 k bf16 direct copy
#pragma unroll
        for (int i = 0; i < 2; ++i) {
            int idx = tid + i * 256;          // 0..511
            int col = idx >> 2, q = idx & 3;  // q: 16B chunk in 64B col-slab
            uint4 v = *(const uint4*)&wb[(size_t)(colBase + col) * IN_C + k0 + q * 8];
            *(uint4*)&Bs[col * 40 + q * 8] = v;
        }
        __syncthreads();

        bf16x8 a[4], b[4];
#pragma unroll
        for (int mi = 0; mi < 4; ++mi)
            a[mi] = *(const bf16x8*)&As[(wr * 64 + mi * 16 + r0) * 40 + kg * 8];
#pragma unroll
        for (int ni = 0; ni < 4; ++ni)
            b[ni] = *(const bf16x8*)&Bs[(wc * 64 + ni * 16 + r0) * 40 + kg * 8];
#pragma unroll
        for (int mi = 0; mi < 4; ++mi)
#pragma unroll
            for (int ni = 0; ni < 4; ++ni)
                acc[mi][ni] = __builtin_amdgcn_mfma_f32_16x16x32_bf16(a[mi], b[ni], acc[mi][ni], 0, 0, 0);
        __syncthreads();
    }

    float bv[4];
#pragma unroll
    for (int ni = 0; ni < 4; ++ni) bv[ni] = bias[colBase + wc * 64 + ni * 16 + r0];

#pragma unroll
    for (int mi = 0; mi < 4; ++mi) {
#pragma unroll
        for (int reg = 0; reg < 4; ++reg) {
            int grow = rowBase + wr * 64 + mi * 16 + kg * 4 + reg;
            if (grow < N) {
#pragma unroll
                for (int ni = 0; ni < 4; ++ni) {
                    float v = acc[mi][ni][reg] + bv[ni];
                    featb[(size_t)grow * OUT_C + colBase + wc * 64 + ni * 16 + r0] = f2bf_rne(v);
                }
            }
        }
    }
}

// ---------------- aggregation: UNCHANGED (measured at BW floor ~241 us; control) ----------------
__device__ __forceinline__ void acc8(float* accf, uint4 v, float wgt) {
    accf[0] += wgt * bflo(v.x); accf[1] += wgt * bfhi(v.x);
    accf[2] += wgt * bflo(v.y); accf[3] += wgt * bfhi(v.y);
    accf[4] += wgt * bflo(v.z); accf[5] += wgt * bfhi(v.z);
    accf[6] += wgt * bflo(v.w); accf[7] += wgt * bfhi(v.w);
}

__global__ __launch_bounds__(256) void k_aggregate(const unsigned short* __restrict__ featb,
                                                   const float* __restrict__ dinv,
                                                   const int* __restrict__ row_start,
                                                   const int* __restrict__ csr_tar,
                                                   float* __restrict__ out, int N) {
    int wave = threadIdx.x >> 6, lane = threadIdx.x & 63;
    int n = blockIdx.x * 4 + wave;
    if (n >= N) return;
    float din = dinv[n];
    int rs = row_start[n], re = row_start[n + 1];
    float accf[8] = {0.f, 0.f, 0.f, 0.f, 0.f, 0.f, 0.f, 0.f};

    for (int base = rs; base < re; base += 64) {
        int m = re - base;
        if (m > 64) m = 64;
        int t_l = 0;
        float w_l = 0.f;
        if (lane < m) {
            t_l = csr_tar[base + lane];
            w_l = din * dinv[t_l];
        }
        int j = 0;
        for (; j + 4 <= m; j += 4) {
            int t0 = __shfl(t_l, j, 64),     t1 = __shfl(t_l, j + 1, 64);
            int t2 = __shfl(t_l, j + 2, 64), t3 = __shfl(t_l, j + 3, 64);
            float w0 = __shfl(w_l, j, 64),     w1 = __shfl(w_l, j + 1, 64);
            float w2 = __shfl(w_l, j + 2, 64), w3 = __shfl(w_l, j + 3, 64);
            uint4 v0 = *(const uint4*)&featb[(size_t)t0 * OUT_C + lane * 8];
            uint4 v1 = *(const uint4*)&featb[(size_t)t1 * OUT_C + lane * 8];
            uint4 v2 = *(const uint4*)&featb[(size_t)t2 * OUT_C + lane * 8];
            uint4 v3 = *(const uint4*)&featb[(size_t)t3 * OUT_C + lane * 8];
            acc8(accf, v0, w0);
            acc8(accf, v1, w1);
            acc8(accf, v2, w2);
            acc8(accf, v3, w3);
        }
        for (; j < m; ++j) {
            int t = __shfl(t_l, j, 64);
            float w = __shfl(w_l, j, 64);
            uint4 v = *(const uint4*)&featb[(size_t)t * OUT_C + lane * 8];
            acc8(accf, v, w);
        }
    }

    // self contribution: feat[n] * dinv^2
    {
        uint4 v = *(const uint4*)&featb[(size_t)n * OUT_C + lane * 8];
        acc8(accf, v, din * din);
    }
    float4 o0 = {accf[0], accf[1], accf[2], accf[3]};
    float4 o1 = {accf[4], accf[5], accf[6], accf[7]};
    *(float4*)&out[(size_t)n * OUT_C + lane * 8] = o0;
    *(float4*)&out[(size_t)n * OUT_C + lane * 8 + 4] = o1;
}

extern "C" void kernel_launch(void* const* d_in, const int* in_sizes, int n_in,
                              void* d_out, int out_size, void* d_ws, size_t ws_size,
                              hipStream_t stream) {
    const float* x    = (const float*)d_in[0];
    const int*   ei   = (const int*)d_in[1];
    const float* W    = (const float*)d_in[2];
    const float* bias = (const float*)d_in[3];
    float* out = (float*)d_out;

    int N = in_sizes[0] / IN_C;     // 50000
    int E = in_sizes[1] / 2;        // 1600000
    const int* src = ei;
    const int* tar = ei + E;
    int nb = (N + 1023) >> 10;      // scan blocks (49)

    // workspace layout (~59 MB)
    char* ws = (char*)d_ws;
    unsigned short* featb = (unsigned short*)ws;                      // 51.2 MB
    size_t off = (size_t)N * OUT_C * sizeof(unsigned short);
    unsigned short* wb = (unsigned short*)(ws + off);                 // 0.52 MB
    off += (size_t)OUT_C * IN_C * sizeof(unsigned short);
    float* dinv = (float*)(ws + off);      off += (size_t)N * sizeof(float);
    int* deg = (int*)(ws + off);           off += (size_t)N * sizeof(int);
    int* fill = (int*)(ws + off);          off += (size_t)N * sizeof(int);   // adjacent to deg
    int* row_start = (int*)(ws + off);     off += (size_t)(N + 1) * sizeof(int);
    int* bsum = (int*)(ws + off);          off += (size_t)(nb + 1) * sizeof(int);
    int* csr_tar = (int*)(ws + off);       off += (size_t)E * sizeof(int);

    // ---- phase 1: W convert + fused convert/GEMM ----
    int n8w = OUT_C * IN_C / 8;
    k_convert<<<(n8w + 255) / 256, 256, 0, stream>>>(W, wb, n8w);
    dim3 g(OUT_C / 128, (N + 127) / 128);
    k_gemm_fused<<<g, 256, 0, stream>>>(x, wb, bias, featb, N);

    // ---- phase 2: CSR build ----
    (void)hipMemsetAsync(deg, 0, 2 * (size_t)N * sizeof(int), stream);
    k_degree<<<(E + 255) / 256, 256, 0, stream>>>(src, E, deg);
    k_scan1<<<nb, 1024, 0, stream>>>(deg, N, row_start, bsum, dinv);
    k_scan3<<<(N + 255) / 256, 256, 0, stream>>>(row_start, bsum, N, E);
    k_fill<<<(E + 255) / 256, 256, 0, stream>>>(src, tar, E, row_start, fill, csr_tar);

    // ---- phase 3: aggregate ----
    k_aggregate<<<(N + 3) / 4, 256, 0, stream>>>(featb, dinv, row_start, csr_tar, out, N);
}